// Round 8
// baseline (6239.663 us; speedup 1.0000x reference)
//
#include <hip/hip_runtime.h>

typedef _Float16 half8 __attribute__((ext_vector_type(8)));
typedef _Float16 half4_t __attribute__((ext_vector_type(4)));
typedef _Float16 half2_t __attribute__((ext_vector_type(2)));
typedef float f32x4 __attribute__((ext_vector_type(4)));
typedef float f32x2 __attribute__((ext_vector_type(2)));
typedef unsigned long long u64;
typedef unsigned int u32;

#define SCALE 0.03125f   // 1/sqrt(1024)

// workspace layout (bytes)
#define XZ_OFF   0ULL            // f16 [8192][2048]  33,554,432
#define RING_OFF 33554432ULL     // ring: 128 slots x 131072 B = 16,777,216 (xbf reused)
#define XBF_OFF  33554432ULL
#define WXZ_OFF  50331648ULL     // f16 [2048][1024]   4,194,304
#define WH_OFF   54525952ULL     // f16 [1024][1024]   2,097,152
#define WW_OFF   56623104ULL     // f16 [1024][1024]   2,097,152
#define VOTE_OFF 58720256ULL     // u32 [32][4] (16B stride)   512  (memset'd)
#define MB_OFF   58720768ULL     // u32 mb1[32][32][16], mb2[32][32][16] = 131,072 (NOT memset)
// ring slot internal offsets:
#define R_W   0        // f32 [32][256]  32,768
#define R_A   32768    // f32 [32][256]  32,768
#define R_C   65536    // f32 [32][16]    2,048
#define R_H   67584    // u64 [4096]     32,768
#define SLOT  131072

union PkH { u64 u; half4_t h; u32 w[2]; };
union PkW { u32 u; half2_t h; };

// ---- transport helpers: uniform `mall` flag picks MALL (proven R4) vs same-XCD L2 ----
__device__ __forceinline__ float ldf(const float* p, bool mall) {
    return mall ? __hip_atomic_load(p, __ATOMIC_RELAXED, __HIP_MEMORY_SCOPE_AGENT) : *p;
}
__device__ __forceinline__ void stf(float* p, float v, bool mall) {
    if (mall) __hip_atomic_store(p, v, __ATOMIC_RELAXED, __HIP_MEMORY_SCOPE_AGENT); else *p = v;
}
__device__ __forceinline__ u64 ldq(const u64* p, bool mall) {
    return mall ? __hip_atomic_load(p, __ATOMIC_RELAXED, __HIP_MEMORY_SCOPE_AGENT) : *p;
}
__device__ __forceinline__ void stq(u64* p, u64 v, bool mall) {
    if (mall) __hip_atomic_store(p, v, __ATOMIC_RELAXED, __HIP_MEMORY_SCOPE_AGENT); else *p = v;
}
// mailbox words: atomics execute at TCC (L2) — never L1-served; MALL path = agent atomics
__device__ __forceinline__ u32 ldsen(u32* p, bool mall) {
    return mall ? __hip_atomic_load(p, __ATOMIC_RELAXED, __HIP_MEMORY_SCOPE_AGENT) : atomicAdd(p, 0u);
}
__device__ __forceinline__ void stsen(u32* p, u32 v, bool mall) {
    if (mall) __hip_atomic_store(p, v, __ATOMIC_RELAXED, __HIP_MEMORY_SCOPE_AGENT); else atomicExch(p, v);
}

__global__ void cvt_kernel(const float* __restrict__ in, _Float16* __restrict__ o, int n4) {
    int i = blockIdx.x * 256 + threadIdx.x;
    if (i < n4) {
        f32x4 v = ((const f32x4*)in)[i];
        half4_t h;
        h[0] = (_Float16)v[0]; h[1] = (_Float16)v[1];
        h[2] = (_Float16)v[2]; h[3] = (_Float16)v[3];
        ((half4_t*)o)[i] = h;
    }
}

// xz[m][n] = sum_k x[m][k] * Wxz[n][k];  M=8192, N=2048, K=1024
__launch_bounds__(256, 1)
__global__ void gemm_xz(const _Float16* __restrict__ A,
                        const _Float16* __restrict__ Bw,
                        _Float16* __restrict__ C) {
    __shared__ _Float16 As[128 * 40];
    __shared__ _Float16 Bs[128 * 40];
    const int tid = threadIdx.x;
    const int m0 = blockIdx.y * 128, n0 = blockIdx.x * 128;
    const int w = tid >> 6, lane = tid & 63;
    const int mw = (w >> 1) * 64, nw = (w & 1) * 64;
    const int row = lane & 15, q = lane >> 4;
    f32x4 acc[4][4];
    #pragma unroll
    for (int mt = 0; mt < 4; mt++)
        #pragma unroll
        for (int nt = 0; nt < 4; nt++)
            acc[mt][nt] = (f32x4){0.f, 0.f, 0.f, 0.f};

    for (int k0 = 0; k0 < 1024; k0 += 32) {
        __syncthreads();
        for (int cc = tid; cc < 512; cc += 256) {
            int r = cc >> 2, kc = (cc & 3) * 8;
            *(half8*)(&As[r * 40 + kc]) = *(const half8*)(&A[(size_t)(m0 + r) * 1024 + k0 + kc]);
            *(half8*)(&Bs[r * 40 + kc]) = *(const half8*)(&Bw[(size_t)(n0 + r) * 1024 + k0 + kc]);
        }
        __syncthreads();
        half8 af[4], bf[4];
        #pragma unroll
        for (int mt = 0; mt < 4; mt++) af[mt] = *(const half8*)(&As[(mw + mt * 16 + row) * 40 + q * 8]);
        #pragma unroll
        for (int nt = 0; nt < 4; nt++) bf[nt] = *(const half8*)(&Bs[(nw + nt * 16 + row) * 40 + q * 8]);
        #pragma unroll
        for (int mt = 0; mt < 4; mt++)
            #pragma unroll
            for (int nt = 0; nt < 4; nt++)
                acc[mt][nt] = __builtin_amdgcn_mfma_f32_16x16x32_f16(af[mt], bf[nt], acc[mt][nt], 0, 0, 0);
    }
    #pragma unroll
    for (int mt = 0; mt < 4; mt++)
        #pragma unroll
        for (int nt = 0; nt < 4; nt++)
            #pragma unroll
            for (int r = 0; r < 4; r++) {
                int gm = m0 + mw + mt * 16 + q * 4 + r;
                int gn = n0 + nw + nt * 16 + row;
                C[(size_t)gm * 2048 + gn] = (_Float16)acc[mt][nt][r];
            }
}

// Persistent scan: participants = blockIdx%8==0 (32 blocks, one XCD under round-robin
// dispatch; verified by XCC vote -> else MALL fallback). Handshake: PRIVATE mailboxes
// mb[consumer][producer] (64B stride) — producer pushes to 32 consumer-private lines,
// consumer polls only its own 32 lines (4 pollers/line, no cross-block RMW contention).
// Values are equality-checked monotone step counters (poison/stale immune).
// Payloads: 128-slot ring (L1-cold by reuse distance), plain loads/stores via shared L2.
__launch_bounds__(256, 1)
__global__ void scan_kernel(const _Float16* __restrict__ xz,   // [8192][2048]
                            const float* __restrict__ tape_in, // [16][16][1024]
                            const float* __restrict__ h_in,    // [16][1024]
                            const float* __restrict__ bh,      // [1024]
                            const _Float16* __restrict__ wh,   // [1024][1024]
                            const _Float16* __restrict__ ww,   // [1024][1024]
                            char* ring,                        // 128 x SLOT
                            u32* mb,                           // mb1[16384], mb2[16384]
                            u32* vote,                         // [32*4]
                            float* __restrict__ out) {
    if (blockIdx.x & 7) return;               // non-participants exit immediately
    const int s = blockIdx.x >> 3;            // 0..31

    __shared__ _Float16 h_l[16 * 1032];
    __shared__ float tape_l[256 * 33];
    __shared__ float wv_l[16 * 33];
    __shared__ float hn_l[16 * 33];
    __shared__ float red_l[8 * 256];
    __shared__ float pad_l[820];              // pads LDS > 80 KiB: forces 1 block/CU
    __shared__ int sh_same;

    const int tid = threadIdx.x;
    { volatile float* vp = pad_l; vp[tid & 255] = 0.f; }   // keep pad_l live

    // ---- XCC vote via MALL atomics (memset-initialized) ----
    if (tid == 0) {
        u32 xcc;
        asm volatile("s_getreg_b32 %0, hwreg(HW_REG_XCC_ID)" : "=s"(xcc));
        xcc &= 7u;
        __hip_atomic_store(&vote[s * 4], xcc + 1u, __ATOMIC_RELAXED, __HIP_MEMORY_SCOPE_AGENT);
        int same = 1; u32 ref = 0;
        for (int i = 0; i < 32; i++) {
            u32 v; int spin = 0;
            while ((v = __hip_atomic_load(&vote[i * 4], __ATOMIC_RELAXED, __HIP_MEMORY_SCOPE_AGENT)) == 0u) {
                if (++spin > 1000000) { v = 0xFFFFFFFFu; break; }
                __builtin_amdgcn_s_sleep(2);
            }
            if (i == 0) ref = v;
            if (v != ref || v == 0xFFFFFFFFu) same = 0;
        }
        sh_same = same;
    }
    __syncthreads();
    const bool mall = (sh_same == 0);   // uniform fallback to MALL transport if not one XCD

    const int w = tid >> 6, lane = tid & 63;
    const int bi = tid >> 4, ni = tid & 15;   // (batch, slot-pair) mapping
    const int ci = tid & 31, gi = tid >> 5;   // prologue tape fill mapping
    const int gbase = lane & 48;              // 16-lane group base within wave
    u32* mb1 = mb;            // phase-1 ready: mb1[consumer*512 + producer*16]
    u32* mb2 = mb + 16384;    // phase-2 ready
    bool dead = false;

    // ---- W fragment preload (pinned in VGPRs for all 512 steps) ----
    half8 whf[2][8], wwf[2][8];
    {
        const int fr = lane & 15, fq = lane >> 4;
        #pragma unroll
        for (int nt = 0; nt < 2; nt++)
            #pragma unroll
            for (int kk = 0; kk < 8; kk++) {
                int gcol = s * 32 + nt * 16 + fr;
                int gk = w * 256 + kk * 32 + fq * 8;
                whf[nt][kk] = *(const half8*)(&wh[(size_t)gcol * 1024 + gk]);
                wwf[nt][kk] = *(const half8*)(&ww[(size_t)gcol * 1024 + gk]);
            }
    }
    // ---- prologue: tape -> LDS; publish h0, zero W/C, A partials into ring slot 0 ----
    for (int j = 0; j < 32; j++) {
        int bn = gi + (j << 3);
        tape_l[bn * 33 + ci] = tape_in[(size_t)bn * 1024 + s * 32 + ci];
    }
    const int c0 = 2 * ni, c1 = c0 + 1;
    {
        char* sp0 = ring;   // slot 0
        float h0a = h_in[(size_t)bi * 1024 + s * 32 + c0];
        float h0b = h_in[(size_t)bi * 1024 + s * 32 + c1];
        PkW me; me.h = (half2_t){(_Float16)h0a, (_Float16)h0b};
        u32 other = __shfl_xor(me.u, 1);
        if (!(ni & 1)) {
            PkH pk; pk.w[0] = me.u; pk.w[1] = other;
            stq(&((u64*)(sp0 + R_H))[bi * 256 + s * 8 + (ni >> 1)], pk.u, mall);
        }
        stf(&((float*)(sp0 + R_W))[s * 256 + tid], 0.f, mall);
        if (tid < 16) stf(&((float*)(sp0 + R_C))[s * 16 + tid], 0.f, mall);
    }
    __syncthreads();
    {
        float asum = 0.f;
        for (int c2 = 0; c2 < 32; c2++)
            asum += h_in[(size_t)bi * 1024 + s * 32 + c2] * tape_l[tid * 33 + c2];
        stf(&((float*)(ring + R_A))[s * 256 + tid], asum, mall);
    }
    __syncthreads();   // vmcnt drain: all publishes visible at coherence point
    if (tid < 32) stsen(&mb2[tid * 512 + s * 16], 1u, mall);   // push to each consumer

    const f32x2 bhp = *(const f32x2*)(&bh[s * 32 + c0]);
    float wv0 = 0.f, wv1 = 0.f;   // own write_val pair (from previous step)
    float asumR = 0.f;            // A partial sum (prefetched in phase 2)
    const int nt0 = c0 >> 4, cl0 = c0 & 15, nt1 = c1 >> 4, cl1 = c1 & 15;
    const int rln = ((bi >> 2) * 16) * 4 + (bi & 3);

    for (int t = 0; t < 512; t++) {
        char* sp  = ring + (size_t)(t & 127) * SLOT;          // slot consumed at step t
        char* spn = ring + (size_t)((t + 1) & 127) * SLOT;    // slot produced for step t+1
        // ================= Phase 1: h_t, out_t =================
        const size_t m = (size_t)bi * 512 + t;
        const half2_t xp2 = *(const half2_t*)(&xz[m * 2048 + s * 32 + c0]);
        const half2_t zz2 = *(const half2_t*)(&xz[m * 2048 + 1024 + s * 32 + c0]);
        // wait: poll own private mailbox row (lane<32 of each wave; 4 pollers/line)
        if (!dead && lane < 32) {
            int spin = 0;
            while (ldsen(&mb2[s * 512 + lane * 16], mall) != (u32)(t + 1)) {
                if (++spin > 2000000) { dead = true; break; }
                __builtin_amdgcn_s_sleep(1);
            }
        }
        asm volatile("" ::: "memory");   // no load hoisting above the poll
        // single-shot payload reads
        float wsum = 0.f;
        {
            const float* rW = (const float*)(sp + R_W);
            #pragma unroll
            for (int s2 = 0; s2 < 32; s2++) wsum += ldf(&rW[s2 * 256 + tid], mall);
        }
        float csum = 0.f;
        if (lane < 4) {
            const float* rC = (const float*)(sp + R_C);
            int b = w * 4 + lane;
            float cs = 0.f;
            #pragma unroll
            for (int s2 = 0; s2 < 32; s2++) cs += ldf(&rC[s2 * 16 + b], mall);
            csum = cs;
        }
        csum = __shfl(csum, lane >> 4);   // group g <- lane g (batch w*4+g)
        if (t == 0) {
            const float* rA = (const float*)(sp + R_A);
            float a = 0.f;
            #pragma unroll
            for (int s2 = 0; s2 < 32; s2++) a += ldf(&rA[s2 * 256 + tid], mall);
            asumR = a;
            const u64* rH = (const u64*)(sp + R_H);
            #pragma unroll
            for (int j = 0; j < 16; j++) {
                int idx = j * 256 + tid;
                PkH pk; pk.u = ldq(&rH[idx], mall);
                *(half4_t*)(&h_l[(idx >> 8) * 1032 + (idx & 255) * 4]) = pk.h;
            }
            __syncthreads();
        }
        // softmaxes (16-lane groups)
        float wa = 0.f, rs = asumR;
        if (t > 0) {
            float v = wsum * SCALE;
            float mx = v;
            for (int d2 = 1; d2 < 16; d2 <<= 1) mx = fmaxf(mx, __shfl_xor(mx, d2, 16));
            float e = __expf(v - mx);
            float sm = e;
            for (int d2 = 1; d2 < 16; d2 <<= 1) sm += __shfl_xor(sm, d2, 16);
            wa = e / sm;
            rs = (1.f - wa) * asumR + wa * csum;
        }
        float ra;
        {
            float v = rs * SCALE;
            float mx = v;
            for (int d2 = 1; d2 < 16; d2 <<= 1) mx = fmaxf(mx, __shfl_xor(mx, d2, 16));
            float e = __expf(v - mx);
            float sm = e;
            for (int d2 = 1; d2 < 16; d2 <<= 1) sm += __shfl_xor(sm, d2, 16);
            ra = e / sm;
        }
        // lazy tape update (write of step t-1) + read_val — wave-local via shfl
        float rv0 = 0.f, rv1 = 0.f;
        {
            const int base = bi * 16;
            #pragma unroll
            for (int n = 0; n < 16; n++) {
                float f = __shfl(wa, gbase + n);
                float r = __shfl(ra, gbase + n);
                int idx = (base + n) * 33 + c0;
                float t0 = tape_l[idx], t1 = tape_l[idx + 1];
                t0 += f * (wv0 - t0); t1 += f * (wv1 - t1);
                tape_l[idx] = t0; tape_l[idx + 1] = t1;
                rv0 += r * t0; rv1 += r * t1;
            }
        }
        // MFMA1: W_h slice × h_{t-1} (h_l persisted from previous phase 2)
        {
            f32x4 a0 = (f32x4){0.f, 0.f, 0.f, 0.f}, a1 = (f32x4){0.f, 0.f, 0.f, 0.f};
            const int row = lane & 15, q = lane >> 4, kb = w * 256;
            #pragma unroll
            for (int kk = 0; kk < 8; kk++) {
                half8 af = *(const half8*)(&h_l[row * 1032 + kb + kk * 32 + q * 8]);
                a0 = __builtin_amdgcn_mfma_f32_16x16x32_f16(af, whf[0][kk], a0, 0, 0, 0);
                a1 = __builtin_amdgcn_mfma_f32_16x16x32_f16(af, whf[1][kk], a1, 0, 0, 0);
            }
            *(f32x4*)(&red_l[(w * 2 + 0) * 256 + lane * 4]) = a0;
            *(f32x4*)(&red_l[(w * 2 + 1) * 256 + lane * 4]) = a1;
        }
        __syncthreads();   // S2: red_l ready
        // epilogue
        float o0, o1;
        {
            float v0 = red_l[nt0 * 256 + cl0 * 4 + rln] + red_l[(2 + nt0) * 256 + cl0 * 4 + rln]
                     + red_l[(4 + nt0) * 256 + cl0 * 4 + rln] + red_l[(6 + nt0) * 256 + cl0 * 4 + rln];
            float v1 = red_l[nt1 * 256 + cl1 * 4 + rln] + red_l[(2 + nt1) * 256 + cl1 * 4 + rln]
                     + red_l[(4 + nt1) * 256 + cl1 * 4 + rln] + red_l[(6 + nt1) * 256 + cl1 * 4 + rln];
            float hv0 = tanhf(v0 + (float)xp2[0] + rv0 + bhp[0]);
            float hv1 = tanhf(v1 + (float)xp2[1] + rv1 + bhp[1]);
            float g0 = (float)zz2[0] + rv0 + hv0;
            float g1 = (float)zz2[1] + rv1 + hv1;
            o0 = hv0 * g0 / (1.f + __expf(-g0));
            o1 = hv1 * g1 / (1.f + __expf(-g1));
            hn_l[bi * 33 + c0] = hv0; hn_l[bi * 33 + c1] = hv1;
            // publish h_t into next slot (lane-pair shfl, even-ni stores u64)
            PkW me; me.h = (half2_t){(_Float16)hv0, (_Float16)hv1};
            u32 other = __shfl_xor(me.u, 1);
            if (!(ni & 1)) {
                PkH pk; pk.w[0] = me.u; pk.w[1] = other;
                stq(&((u64*)(spn + R_H))[bi * 256 + s * 8 + (ni >> 1)], pk.u, mall);
            }
            // A partial (h_t · tape over own cols) — wave-local reads
            float aa = 0.f;
            for (int c2 = 0; c2 < 32; c2++)
                aa += hn_l[bi * 33 + c2] * tape_l[tid * 33 + c2];
            stf(&((float*)(spn + R_A))[s * 256 + tid], aa, mall);
        }
        __syncthreads();   // S3: vmcnt drain (h + A publishes); red_l reads done
        if (tid < 32) stsen(&mb1[tid * 512 + s * 16], (u32)(t + 1), mall);
        // deferred out store (off the mailbox critical path)
        *(f32x2*)(&out[m * 1024 + s * 32 + c0]) = (f32x2){o0, o1};

        // ================= Phase 2: wv_t, score partials =================
        if (!dead && lane < 32) {
            int spin = 0;
            while (ldsen(&mb1[s * 512 + lane * 16], mall) != (u32)(t + 1)) {
                if (++spin > 2000000) { dead = true; break; }
                __builtin_amdgcn_s_sleep(1);
            }
        }
        asm volatile("" ::: "memory");
        // stage h_t and prefetch next-step A partials (slot t+1)
        {
            const u64* rH = (const u64*)(spn + R_H);
            #pragma unroll
            for (int j = 0; j < 16; j++) {
                int idx = j * 256 + tid;
                PkH pk; pk.u = ldq(&rH[idx], mall);
                *(half4_t*)(&h_l[(idx >> 8) * 1032 + (idx & 255) * 4]) = pk.h;
            }
            const float* rA = (const float*)(spn + R_A);
            float a = 0.f;
            #pragma unroll
            for (int s2 = 0; s2 < 32; s2++) a += ldf(&rA[s2 * 256 + tid], mall);
            asumR = a;
        }
        __syncthreads();   // S5: h_l staged
        {
            f32x4 a0 = (f32x4){0.f, 0.f, 0.f, 0.f}, a1 = (f32x4){0.f, 0.f, 0.f, 0.f};
            const int row = lane & 15, q = lane >> 4, kb = w * 256;
            #pragma unroll
            for (int kk = 0; kk < 8; kk++) {
                half8 af = *(const half8*)(&h_l[row * 1032 + kb + kk * 32 + q * 8]);
                a0 = __builtin_amdgcn_mfma_f32_16x16x32_f16(af, wwf[0][kk], a0, 0, 0, 0);
                a1 = __builtin_amdgcn_mfma_f32_16x16x32_f16(af, wwf[1][kk], a1, 0, 0, 0);
            }
            *(f32x4*)(&red_l[(w * 2 + 0) * 256 + lane * 4]) = a0;
            *(f32x4*)(&red_l[(w * 2 + 1) * 256 + lane * 4]) = a1;
        }
        __syncthreads();   // S6: red_l ready
        wv0 = red_l[nt0 * 256 + cl0 * 4 + rln] + red_l[(2 + nt0) * 256 + cl0 * 4 + rln]
            + red_l[(4 + nt0) * 256 + cl0 * 4 + rln] + red_l[(6 + nt0) * 256 + cl0 * 4 + rln];
        wv1 = red_l[nt1 * 256 + cl1 * 4 + rln] + red_l[(2 + nt1) * 256 + cl1 * 4 + rln]
            + red_l[(4 + nt1) * 256 + cl1 * 4 + rln] + red_l[(6 + nt1) * 256 + cl1 * 4 + rln];
        wv_l[bi * 33 + c0] = wv0; wv_l[bi * 33 + c1] = wv1;
        // W/C partials into slot t+1
        {
            float ws = 0.f;
            for (int c2 = 0; c2 < 32; c2++)
                ws += wv_l[bi * 33 + c2] * tape_l[tid * 33 + c2];
            stf(&((float*)(spn + R_W))[s * 256 + tid], ws, mall);
            float cpart = hn_l[bi * 33 + c0] * wv0 + hn_l[bi * 33 + c1] * wv1;
            for (int d2 = 1; d2 < 16; d2 <<= 1) cpart += __shfl_xor(cpart, d2, 16);
            if (ni == 0) stf(&((float*)(spn + R_C))[s * 16 + bi], cpart, mall);
        }
        __syncthreads();   // S7: vmcnt drain
        if (tid < 32) stsen(&mb2[tid * 512 + s * 16], (u32)(t + 2), mall);
    }
    // ================= finale: apply last tape update, write h_tape_final =================
    if (!dead && lane < 32) {
        int spin = 0;
        while (ldsen(&mb2[s * 512 + lane * 16], mall) != 513u) {
            if (++spin > 2000000) { dead = true; break; }
            __builtin_amdgcn_s_sleep(1);
        }
    }
    asm volatile("" ::: "memory");
    float waF;
    {
        const float* rW = (const float*)(ring + (size_t)(512 & 127) * SLOT + R_W);
        float wsum = 0.f;
        #pragma unroll
        for (int s2 = 0; s2 < 32; s2++) wsum += ldf(&rW[s2 * 256 + tid], mall);
        float v = wsum * SCALE;
        float mx = v;
        for (int d2 = 1; d2 < 16; d2 <<= 1) mx = fmaxf(mx, __shfl_xor(mx, d2, 16));
        float e = __expf(v - mx);
        float sm = e;
        for (int d2 = 1; d2 < 16; d2 <<= 1) sm += __shfl_xor(sm, d2, 16);
        waF = e / sm;
    }
    {
        const int base = bi * 16;
        #pragma unroll
        for (int n = 0; n < 16; n++) {
            float f = __shfl(waF, gbase + n);
            int idx = (base + n) * 33 + c0;
            float t0 = tape_l[idx], t1 = tape_l[idx + 1];
            t0 += f * (wv0 - t0); t1 += f * (wv1 - t1);
            *(f32x2*)(&out[8388608ULL + (size_t)(base + n) * 1024 + s * 32 + c0]) = (f32x2){t0, t1};
        }
    }
}

extern "C" void kernel_launch(void* const* d_in, const int* in_sizes, int n_in,
                              void* d_out, int out_size, void* d_ws, size_t ws_size,
                              hipStream_t stream) {
    const float* x     = (const float*)d_in[0];
    const float* tape0 = (const float*)d_in[1];
    const float* h0    = (const float*)d_in[2];
    const float* Wh    = (const float*)d_in[3];
    const float* Wxz   = (const float*)d_in[4];
    const float* bh    = (const float*)d_in[5];
    const float* Ww    = (const float*)d_in[6];

    char* ws = (char*)d_ws;
    _Float16* xbf   = (_Float16*)(ws + XBF_OFF);
    _Float16* wxzbf = (_Float16*)(ws + WXZ_OFF);
    _Float16* whbf  = (_Float16*)(ws + WH_OFF);
    _Float16* wwbf  = (_Float16*)(ws + WW_OFF);
    _Float16* xzbf  = (_Float16*)(ws + XZ_OFF);
    char* ring      = ws + RING_OFF;
    u32* vote       = (u32*)(ws + VOTE_OFF);
    u32* mb         = (u32*)(ws + MB_OFF);

    hipMemsetAsync(ws + VOTE_OFF, 0, 512, stream);   // vote words only

    cvt_kernel<<<8192, 256, 0, stream>>>(x, xbf, 2097152);
    cvt_kernel<<<2048, 256, 0, stream>>>(Wxz, wxzbf, 524288);
    cvt_kernel<<<1024, 256, 0, stream>>>(Wh, whbf, 262144);
    cvt_kernel<<<1024, 256, 0, stream>>>(Ww, wwbf, 262144);

    gemm_xz<<<dim3(16, 64), 256, 0, stream>>>(xbf, wxzbf, xzbf);

    scan_kernel<<<256, 256, 0, stream>>>(xzbf, tape0, h0, bh, whbf, wwbf,
                                         ring, mb, vote, (float*)d_out);
}

// Round 9
// 5586.683 us; speedup vs baseline: 1.1169x; 1.1169x over previous
//
#include <hip/hip_runtime.h>

typedef _Float16 half8 __attribute__((ext_vector_type(8)));
typedef _Float16 half4_t __attribute__((ext_vector_type(4)));
typedef _Float16 half2_t __attribute__((ext_vector_type(2)));
typedef float f32x4 __attribute__((ext_vector_type(4)));
typedef float f32x2 __attribute__((ext_vector_type(2)));
typedef unsigned long long u64;
typedef unsigned int u32;

#define SCALE 0.03125f   // 1/sqrt(1024)

// workspace layout (bytes)
#define XZ_OFF   0ULL            // f16 [8192][2048]  33,554,432
#define RING_OFF 33554432ULL     // ring: 128 slots x 131072 B = 16,777,216 (xbf reused)
#define XBF_OFF  33554432ULL
#define WXZ_OFF  50331648ULL     // f16 [2048][1024]   4,194,304
#define WH_OFF   54525952ULL     // f16 [1024][1024]   2,097,152
#define WW_OFF   56623104ULL     // f16 [1024][1024]   2,097,152
#define VOTE_OFF 58720256ULL     // u32 [32][4] (16B stride)   512  (memset'd)
#define SEN_OFF  58720768ULL     // u32 sen1[32][32], sen2[32][32] (128B stride) 8,192 (NOT memset)
// ring slot internal offsets:
#define R_W   0        // f32 [32][256]  32,768
#define R_A   32768    // f32 [32][256]  32,768
#define R_C   65536    // f32 [32][16]    2,048
#define R_H   67584    // u64 [4096]     32,768  (h: [16 batch][256 u64], 4 f16/u64)
#define SLOT  131072

union PkH { u64 u; half4_t h; u32 w[2]; };
union PkW { u32 u; half2_t h; };
union Pk2 { u64 u[2]; half8 h8; };

// ---- transport helpers: uniform `mall` flag picks MALL (proven R4) vs same-XCD L2 ----
__device__ __forceinline__ float ldf(const float* p, bool mall) {
    return mall ? __hip_atomic_load(p, __ATOMIC_RELAXED, __HIP_MEMORY_SCOPE_AGENT) : *p;
}
__device__ __forceinline__ void stf(float* p, float v, bool mall) {
    if (mall) __hip_atomic_store(p, v, __ATOMIC_RELAXED, __HIP_MEMORY_SCOPE_AGENT); else *p = v;
}
__device__ __forceinline__ u64 ldq(const u64* p, bool mall) {
    return mall ? __hip_atomic_load(p, __ATOMIC_RELAXED, __HIP_MEMORY_SCOPE_AGENT) : *p;
}
__device__ __forceinline__ void stq(u64* p, u64 v, bool mall) {
    if (mall) __hip_atomic_store(p, v, __ATOMIC_RELAXED, __HIP_MEMORY_SCOPE_AGENT); else *p = v;
}
// sentinels: atomics execute at TCC (L2) — never L1-served
__device__ __forceinline__ u32 ldsen(u32* p, bool mall) {
    return mall ? __hip_atomic_load(p, __ATOMIC_RELAXED, __HIP_MEMORY_SCOPE_AGENT) : atomicAdd(p, 0u);
}
__device__ __forceinline__ void stsen(u32* p, u32 v, bool mall) {
    if (mall) __hip_atomic_store(p, v, __ATOMIC_RELAXED, __HIP_MEMORY_SCOPE_AGENT); else atomicExch(p, v);
}

__global__ void cvt_kernel(const float* __restrict__ in, _Float16* __restrict__ o, int n4) {
    int i = blockIdx.x * 256 + threadIdx.x;
    if (i < n4) {
        f32x4 v = ((const f32x4*)in)[i];
        half4_t h;
        h[0] = (_Float16)v[0]; h[1] = (_Float16)v[1];
        h[2] = (_Float16)v[2]; h[3] = (_Float16)v[3];
        ((half4_t*)o)[i] = h;
    }
}

// xz[m][n] = sum_k x[m][k] * Wxz[n][k];  M=8192, N=2048, K=1024
__launch_bounds__(256, 1)
__global__ void gemm_xz(const _Float16* __restrict__ A,
                        const _Float16* __restrict__ Bw,
                        _Float16* __restrict__ C) {
    __shared__ _Float16 As[128 * 40];
    __shared__ _Float16 Bs[128 * 40];
    const int tid = threadIdx.x;
    const int m0 = blockIdx.y * 128, n0 = blockIdx.x * 128;
    const int w = tid >> 6, lane = tid & 63;
    const int mw = (w >> 1) * 64, nw = (w & 1) * 64;
    const int row = lane & 15, q = lane >> 4;
    f32x4 acc[4][4];
    #pragma unroll
    for (int mt = 0; mt < 4; mt++)
        #pragma unroll
        for (int nt = 0; nt < 4; nt++)
            acc[mt][nt] = (f32x4){0.f, 0.f, 0.f, 0.f};

    for (int k0 = 0; k0 < 1024; k0 += 32) {
        __syncthreads();
        for (int cc = tid; cc < 512; cc += 256) {
            int r = cc >> 2, kc = (cc & 3) * 8;
            *(half8*)(&As[r * 40 + kc]) = *(const half8*)(&A[(size_t)(m0 + r) * 1024 + k0 + kc]);
            *(half8*)(&Bs[r * 40 + kc]) = *(const half8*)(&Bw[(size_t)(n0 + r) * 1024 + k0 + kc]);
        }
        __syncthreads();
        half8 af[4], bf[4];
        #pragma unroll
        for (int mt = 0; mt < 4; mt++) af[mt] = *(const half8*)(&As[(mw + mt * 16 + row) * 40 + q * 8]);
        #pragma unroll
        for (int nt = 0; nt < 4; nt++) bf[nt] = *(const half8*)(&Bs[(nw + nt * 16 + row) * 40 + q * 8]);
        #pragma unroll
        for (int mt = 0; mt < 4; mt++)
            #pragma unroll
            for (int nt = 0; nt < 4; nt++)
                acc[mt][nt] = __builtin_amdgcn_mfma_f32_16x16x32_f16(af[mt], bf[nt], acc[mt][nt], 0, 0, 0);
    }
    #pragma unroll
    for (int mt = 0; mt < 4; mt++)
        #pragma unroll
        for (int nt = 0; nt < 4; nt++)
            #pragma unroll
            for (int r = 0; r < 4; r++) {
                int gm = m0 + mw + mt * 16 + q * 4 + r;
                int gn = n0 + nw + nt * 16 + row;
                C[(size_t)gm * 2048 + gn] = (_Float16)acc[mt][nt][r];
            }
}

// Persistent scan: participants = blockIdx%8==0 (one XCD under round-robin dispatch;
// verified by XCC vote -> else MALL fallback). R7 sentinel transport (128B-strided).
// MFMA A-fragments load DIRECTLY from ring H (no LDS staging, no stage barrier);
// MFMA1 hoisted ABOVE the phase-1 poll (h_{t-1} already confirmed last step).
__launch_bounds__(256, 1)
__global__ void scan_kernel(const _Float16* __restrict__ xz,   // [8192][2048]
                            const float* __restrict__ tape_in, // [16][16][1024]
                            const float* __restrict__ h_in,    // [16][1024]
                            const float* __restrict__ bh,      // [1024]
                            const _Float16* __restrict__ wh,   // [1024][1024]
                            const _Float16* __restrict__ ww,   // [1024][1024]
                            char* ring,                        // 128 x SLOT
                            u32* sen,                          // sen1[1024], sen2[1024]
                            u32* vote,                         // [32*4]
                            float* __restrict__ out) {
    if (blockIdx.x & 7) return;               // non-participants exit immediately
    const int s = blockIdx.x >> 3;            // 0..31

    __shared__ float tape_l[256 * 33];
    __shared__ float wv_l[16 * 33];
    __shared__ float hn_l[16 * 33];
    __shared__ float red_l[8 * 256];
    __shared__ float pad_l[9000];             // pads LDS > 80 KiB: forces 1 block/CU
    __shared__ int sh_same;

    const int tid = threadIdx.x;
    { volatile float* vp = pad_l; vp[tid] = 0.f; }   // keep pad_l live

    // ---- XCC vote via MALL atomics (memset-initialized) ----
    if (tid == 0) {
        u32 xcc;
        asm volatile("s_getreg_b32 %0, hwreg(HW_REG_XCC_ID)" : "=s"(xcc));
        xcc &= 7u;
        __hip_atomic_store(&vote[s * 4], xcc + 1u, __ATOMIC_RELAXED, __HIP_MEMORY_SCOPE_AGENT);
        int same = 1; u32 ref = 0;
        for (int i = 0; i < 32; i++) {
            u32 v; int spin = 0;
            while ((v = __hip_atomic_load(&vote[i * 4], __ATOMIC_RELAXED, __HIP_MEMORY_SCOPE_AGENT)) == 0u) {
                if (++spin > 1000000) { v = 0xFFFFFFFFu; break; }
                __builtin_amdgcn_s_sleep(2);
            }
            if (i == 0) ref = v;
            if (v != ref || v == 0xFFFFFFFFu) same = 0;
        }
        sh_same = same;
    }
    __syncthreads();
    const bool mall = (sh_same == 0);   // uniform fallback to MALL transport if not one XCD

    const int w = tid >> 6, lane = tid & 63;
    const int bi = tid >> 4, ni = tid & 15;   // (batch, slot-pair) mapping
    const int ci = tid & 31, gi = tid >> 5;   // prologue tape fill mapping
    const int gbase = lane & 48;              // 16-lane group base within wave
    u32* sen1 = sen;            // [32] stride 32 u32 (128B)
    u32* sen2 = sen + 1024;
    bool dead = false;

    // ---- W fragment preload (pinned in VGPRs for all 512 steps) ----
    half8 whf[2][8], wwf[2][8];
    {
        const int fr = lane & 15, fq = lane >> 4;
        #pragma unroll
        for (int nt = 0; nt < 2; nt++)
            #pragma unroll
            for (int kk = 0; kk < 8; kk++) {
                int gcol = s * 32 + nt * 16 + fr;
                int gk = w * 256 + kk * 32 + fq * 8;
                whf[nt][kk] = *(const half8*)(&wh[(size_t)gcol * 1024 + gk]);
                wwf[nt][kk] = *(const half8*)(&ww[(size_t)gcol * 1024 + gk]);
            }
    }
    // ---- prologue: tape -> LDS; publish h0, zero W/C, A partials into ring slot 0 ----
    for (int j = 0; j < 32; j++) {
        int bn = gi + (j << 3);
        tape_l[bn * 33 + ci] = tape_in[(size_t)bn * 1024 + s * 32 + ci];
    }
    const int c0 = 2 * ni, c1 = c0 + 1;
    {
        char* sp0 = ring;   // slot 0
        float h0a = h_in[(size_t)bi * 1024 + s * 32 + c0];
        float h0b = h_in[(size_t)bi * 1024 + s * 32 + c1];
        PkW me; me.h = (half2_t){(_Float16)h0a, (_Float16)h0b};
        u32 other = __shfl_xor(me.u, 1);
        if (!(ni & 1)) {
            PkH pk; pk.w[0] = me.u; pk.w[1] = other;
            stq(&((u64*)(sp0 + R_H))[bi * 256 + s * 8 + (ni >> 1)], pk.u, mall);
        }
        stf(&((float*)(sp0 + R_W))[s * 256 + tid], 0.f, mall);
        if (tid < 16) stf(&((float*)(sp0 + R_C))[s * 16 + tid], 0.f, mall);
    }
    __syncthreads();
    {
        float asum = 0.f;
        for (int c2 = 0; c2 < 32; c2++)
            asum += h_in[(size_t)bi * 1024 + s * 32 + c2] * tape_l[tid * 33 + c2];
        stf(&((float*)(ring + R_A))[s * 256 + tid], asum, mall);
    }
    __syncthreads();   // vmcnt drain: all publishes visible at coherence point
    if (tid == 0) stsen(&sen2[s * 32], 1u, mall);

    const f32x2 bhp = *(const f32x2*)(&bh[s * 32 + c0]);
    float wv0 = 0.f, wv1 = 0.f;   // own write_val pair (from previous step)
    float asumR = 0.f;            // A partial sum (prefetched in phase 2)
    const int nt0 = c0 >> 4, cl0 = c0 & 15, nt1 = c1 >> 4, cl1 = c1 & 15;
    const int rln = ((bi >> 2) * 16) * 4 + (bi & 3);
    const int frow = lane & 15, fq = lane >> 4, fkb = w * 64 + fq * 2;  // u64-index base for fragments

    for (int t = 0; t < 512; t++) {
        char* sp  = ring + (size_t)(t & 127) * SLOT;          // slot consumed at step t
        char* spn = ring + (size_t)((t + 1) & 127) * SLOT;    // slot produced for step t+1
        const u64* rHp = (const u64*)(sp + R_H);              // h_{t-1}
        // ================= Phase 1: h_t, out_t =================
        const size_t m = (size_t)bi * 512 + t;
        const half2_t xp2 = *(const half2_t*)(&xz[m * 2048 + s * 32 + c0]);
        const half2_t zz2 = *(const half2_t*)(&xz[m * 2048 + 1024 + s * 32 + c0]);
        // MFMA1 (W_h × h_{t-1}) — PRE-POLL for t>0 (h_{t-1} confirmed by last step's sen1 poll)
        if (t > 0) {
            f32x4 a0 = (f32x4){0.f, 0.f, 0.f, 0.f}, a1 = (f32x4){0.f, 0.f, 0.f, 0.f};
            #pragma unroll
            for (int kk = 0; kk < 8; kk++) {
                Pk2 u;
                u.u[0] = ldq(&rHp[frow * 256 + fkb + kk * 8], mall);
                u.u[1] = ldq(&rHp[frow * 256 + fkb + kk * 8 + 1], mall);
                a0 = __builtin_amdgcn_mfma_f32_16x16x32_f16(u.h8, whf[0][kk], a0, 0, 0, 0);
                a1 = __builtin_amdgcn_mfma_f32_16x16x32_f16(u.h8, whf[1][kk], a1, 0, 0, 0);
            }
            *(f32x4*)(&red_l[(w * 2 + 0) * 256 + lane * 4]) = a0;
            *(f32x4*)(&red_l[(w * 2 + 1) * 256 + lane * 4]) = a1;
        }
        __syncthreads();   // S2: red_l ready (t>0); also separates prev-step red_l reads
        // wait: each wave polls all 32 producer sentinels
        if (!dead && lane < 32) {
            int spin = 0;
            while (ldsen(&sen2[lane * 32], mall) < (u32)(t + 1)) {
                if (++spin > 2000000) { dead = true; break; }
                __builtin_amdgcn_s_sleep(1);
            }
        }
        asm volatile("" ::: "memory");   // no load hoisting above the poll
        if (t == 0) {   // h0 publication only confirmed by the poll: MFMA1 post-poll
            f32x4 a0 = (f32x4){0.f, 0.f, 0.f, 0.f}, a1 = (f32x4){0.f, 0.f, 0.f, 0.f};
            #pragma unroll
            for (int kk = 0; kk < 8; kk++) {
                Pk2 u;
                u.u[0] = ldq(&rHp[frow * 256 + fkb + kk * 8], mall);
                u.u[1] = ldq(&rHp[frow * 256 + fkb + kk * 8 + 1], mall);
                a0 = __builtin_amdgcn_mfma_f32_16x16x32_f16(u.h8, whf[0][kk], a0, 0, 0, 0);
                a1 = __builtin_amdgcn_mfma_f32_16x16x32_f16(u.h8, whf[1][kk], a1, 0, 0, 0);
            }
            *(f32x4*)(&red_l[(w * 2 + 0) * 256 + lane * 4]) = a0;
            *(f32x4*)(&red_l[(w * 2 + 1) * 256 + lane * 4]) = a1;
            float a = 0.f;
            const float* rA = (const float*)(sp + R_A);
            #pragma unroll
            for (int s2 = 0; s2 < 32; s2++) a += ldf(&rA[s2 * 256 + tid], mall);
            asumR = a;
            __syncthreads();
        }
        // single-shot payload reads (W, C partials for step t)
        float wsum = 0.f;
        {
            const float* rW = (const float*)(sp + R_W);
            #pragma unroll
            for (int s2 = 0; s2 < 32; s2++) wsum += ldf(&rW[s2 * 256 + tid], mall);
        }
        float csum = 0.f;
        if (lane < 4) {
            const float* rC = (const float*)(sp + R_C);
            int b = w * 4 + lane;
            float cs = 0.f;
            #pragma unroll
            for (int s2 = 0; s2 < 32; s2++) cs += ldf(&rC[s2 * 16 + b], mall);
            csum = cs;
        }
        csum = __shfl(csum, lane >> 4);   // group g <- lane g (batch w*4+g)
        // softmaxes (16-lane groups)
        float wa = 0.f, rs = asumR;
        if (t > 0) {
            float v = wsum * SCALE;
            float mx = v;
            for (int d2 = 1; d2 < 16; d2 <<= 1) mx = fmaxf(mx, __shfl_xor(mx, d2, 16));
            float e = __expf(v - mx);
            float sm = e;
            for (int d2 = 1; d2 < 16; d2 <<= 1) sm += __shfl_xor(sm, d2, 16);
            wa = e / sm;
            rs = (1.f - wa) * asumR + wa * csum;
        }
        float ra;
        {
            float v = rs * SCALE;
            float mx = v;
            for (int d2 = 1; d2 < 16; d2 <<= 1) mx = fmaxf(mx, __shfl_xor(mx, d2, 16));
            float e = __expf(v - mx);
            float sm = e;
            for (int d2 = 1; d2 < 16; d2 <<= 1) sm += __shfl_xor(sm, d2, 16);
            ra = e / sm;
        }
        // lazy tape update (write of step t-1) + read_val — wave-local via shfl
        float rv0 = 0.f, rv1 = 0.f;
        {
            const int base = bi * 16;
            #pragma unroll
            for (int n = 0; n < 16; n++) {
                float f = __shfl(wa, gbase + n);
                float r = __shfl(ra, gbase + n);
                int idx = (base + n) * 33 + c0;
                float t0 = tape_l[idx], t1 = tape_l[idx + 1];
                t0 += f * (wv0 - t0); t1 += f * (wv1 - t1);
                tape_l[idx] = t0; tape_l[idx + 1] = t1;
                rv0 += r * t0; rv1 += r * t1;
            }
        }
        __syncthreads();   // S2b: tape updated (cross-lane reads in epilogue), red_l ready
        // epilogue
        float o0, o1;
        {
            float v0 = red_l[nt0 * 256 + cl0 * 4 + rln] + red_l[(2 + nt0) * 256 + cl0 * 4 + rln]
                     + red_l[(4 + nt0) * 256 + cl0 * 4 + rln] + red_l[(6 + nt0) * 256 + cl0 * 4 + rln];
            float v1 = red_l[nt1 * 256 + cl1 * 4 + rln] + red_l[(2 + nt1) * 256 + cl1 * 4 + rln]
                     + red_l[(4 + nt1) * 256 + cl1 * 4 + rln] + red_l[(6 + nt1) * 256 + cl1 * 4 + rln];
            float hv0 = tanhf(v0 + (float)xp2[0] + rv0 + bhp[0]);
            float hv1 = tanhf(v1 + (float)xp2[1] + rv1 + bhp[1]);
            float g0 = (float)zz2[0] + rv0 + hv0;
            float g1 = (float)zz2[1] + rv1 + hv1;
            o0 = hv0 * g0 / (1.f + __expf(-g0));
            o1 = hv1 * g1 / (1.f + __expf(-g1));
            hn_l[bi * 33 + c0] = hv0; hn_l[bi * 33 + c1] = hv1;
            // publish h_t into next slot (lane-pair shfl, even-ni stores u64)
            PkW me; me.h = (half2_t){(_Float16)hv0, (_Float16)hv1};
            u32 other = __shfl_xor(me.u, 1);
            if (!(ni & 1)) {
                PkH pk; pk.w[0] = me.u; pk.w[1] = other;
                stq(&((u64*)(spn + R_H))[bi * 256 + s * 8 + (ni >> 1)], pk.u, mall);
            }
            // A partial (h_t · tape over own cols) — wave-local reads
            float aa = 0.f;
            for (int c2 = 0; c2 < 32; c2++)
                aa += hn_l[bi * 33 + c2] * tape_l[tid * 33 + c2];
            stf(&((float*)(spn + R_A))[s * 256 + tid], aa, mall);
        }
        __syncthreads();   // S3: vmcnt drain (h + A publishes); red_l reads done
        if (tid == 0) stsen(&sen1[s * 32], (u32)(t + 1), mall);
        // deferred out store (off the sentinel critical path)
        *(f32x2*)(&out[m * 1024 + s * 32 + c0]) = (f32x2){o0, o1};

        // ================= Phase 2: wv_t, score partials =================
        if (!dead && lane < 32) {
            int spin = 0;
            while (ldsen(&sen1[lane * 32], mall) < (u32)(t + 1)) {
                if (++spin > 2000000) { dead = true; break; }
                __builtin_amdgcn_s_sleep(1);
            }
        }
        asm volatile("" ::: "memory");
        // MFMA2 (W_write × h_t) — direct fragment loads from slot t+1 H; A prefetch alongside
        {
            const u64* rHn = (const u64*)(spn + R_H);
            f32x4 a0 = (f32x4){0.f, 0.f, 0.f, 0.f}, a1 = (f32x4){0.f, 0.f, 0.f, 0.f};
            #pragma unroll
            for (int kk = 0; kk < 8; kk++) {
                Pk2 u;
                u.u[0] = ldq(&rHn[frow * 256 + fkb + kk * 8], mall);
                u.u[1] = ldq(&rHn[frow * 256 + fkb + kk * 8 + 1], mall);
                a0 = __builtin_amdgcn_mfma_f32_16x16x32_f16(u.h8, wwf[0][kk], a0, 0, 0, 0);
                a1 = __builtin_amdgcn_mfma_f32_16x16x32_f16(u.h8, wwf[1][kk], a1, 0, 0, 0);
            }
            *(f32x4*)(&red_l[(w * 2 + 0) * 256 + lane * 4]) = a0;
            *(f32x4*)(&red_l[(w * 2 + 1) * 256 + lane * 4]) = a1;
            const float* rA = (const float*)(spn + R_A);
            float a = 0.f;
            #pragma unroll
            for (int s2 = 0; s2 < 32; s2++) a += ldf(&rA[s2 * 256 + tid], mall);
            asumR = a;
        }
        __syncthreads();   // S6: red_l ready
        wv0 = red_l[nt0 * 256 + cl0 * 4 + rln] + red_l[(2 + nt0) * 256 + cl0 * 4 + rln]
            + red_l[(4 + nt0) * 256 + cl0 * 4 + rln] + red_l[(6 + nt0) * 256 + cl0 * 4 + rln];
        wv1 = red_l[nt1 * 256 + cl1 * 4 + rln] + red_l[(2 + nt1) * 256 + cl1 * 4 + rln]
            + red_l[(4 + nt1) * 256 + cl1 * 4 + rln] + red_l[(6 + nt1) * 256 + cl1 * 4 + rln];
        wv_l[bi * 33 + c0] = wv0; wv_l[bi * 33 + c1] = wv1;
        // W/C partials into slot t+1
        {
            float ws = 0.f;
            for (int c2 = 0; c2 < 32; c2++)
                ws += wv_l[bi * 33 + c2] * tape_l[tid * 33 + c2];
            stf(&((float*)(spn + R_W))[s * 256 + tid], ws, mall);
            float cpart = hn_l[bi * 33 + c0] * wv0 + hn_l[bi * 33 + c1] * wv1;
            for (int d2 = 1; d2 < 16; d2 <<= 1) cpart += __shfl_xor(cpart, d2, 16);
            if (ni == 0) stf(&((float*)(spn + R_C))[s * 16 + bi], cpart, mall);
        }
        __syncthreads();   // S7: vmcnt drain
        if (tid == 0) stsen(&sen2[s * 32], (u32)(t + 2), mall);
    }
    // ================= finale: apply last tape update, write h_tape_final =================
    if (!dead && lane < 32) {
        int spin = 0;
        while (ldsen(&sen2[lane * 32], mall) < 513u) {
            if (++spin > 2000000) { dead = true; break; }
            __builtin_amdgcn_s_sleep(1);
        }
    }
    asm volatile("" ::: "memory");
    float waF;
    {
        const float* rW = (const float*)(ring + (size_t)(512 & 127) * SLOT + R_W);
        float wsum = 0.f;
        #pragma unroll
        for (int s2 = 0; s2 < 32; s2++) wsum += ldf(&rW[s2 * 256 + tid], mall);
        float v = wsum * SCALE;
        float mx = v;
        for (int d2 = 1; d2 < 16; d2 <<= 1) mx = fmaxf(mx, __shfl_xor(mx, d2, 16));
        float e = __expf(v - mx);
        float sm = e;
        for (int d2 = 1; d2 < 16; d2 <<= 1) sm += __shfl_xor(sm, d2, 16);
        waF = e / sm;
    }
    {
        const int base = bi * 16;
        #pragma unroll
        for (int n = 0; n < 16; n++) {
            float f = __shfl(waF, gbase + n);
            int idx = (base + n) * 33 + c0;
            float t0 = tape_l[idx], t1 = tape_l[idx + 1];
            t0 += f * (wv0 - t0); t1 += f * (wv1 - t1);
            *(f32x2*)(&out[8388608ULL + (size_t)(base + n) * 1024 + s * 32 + c0]) = (f32x2){t0, t1};
        }
    }
}

extern "C" void kernel_launch(void* const* d_in, const int* in_sizes, int n_in,
                              void* d_out, int out_size, void* d_ws, size_t ws_size,
                              hipStream_t stream) {
    const float* x     = (const float*)d_in[0];
    const float* tape0 = (const float*)d_in[1];
    const float* h0    = (const float*)d_in[2];
    const float* Wh    = (const float*)d_in[3];
    const float* Wxz   = (const float*)d_in[4];
    const float* bh    = (const float*)d_in[5];
    const float* Ww    = (const float*)d_in[6];

    char* ws = (char*)d_ws;
    _Float16* xbf   = (_Float16*)(ws + XBF_OFF);
    _Float16* wxzbf = (_Float16*)(ws + WXZ_OFF);
    _Float16* whbf  = (_Float16*)(ws + WH_OFF);
    _Float16* wwbf  = (_Float16*)(ws + WW_OFF);
    _Float16* xzbf  = (_Float16*)(ws + XZ_OFF);
    char* ring      = ws + RING_OFF;
    u32* vote       = (u32*)(ws + VOTE_OFF);
    u32* sen        = (u32*)(ws + SEN_OFF);

    hipMemsetAsync(ws + VOTE_OFF, 0, 512, stream);   // vote words only

    cvt_kernel<<<8192, 256, 0, stream>>>(x, xbf, 2097152);
    cvt_kernel<<<2048, 256, 0, stream>>>(Wxz, wxzbf, 524288);
    cvt_kernel<<<1024, 256, 0, stream>>>(Wh, whbf, 262144);
    cvt_kernel<<<1024, 256, 0, stream>>>(Ww, wwbf, 262144);

    gemm_xz<<<dim3(16, 64), 256, 0, stream>>>(xbf, wxzbf, xzbf);

    scan_kernel<<<256, 256, 0, stream>>>(xzbf, tape0, h0, bh, whbf, wwbf,
                                         ring, sen, vote, (float*)d_out);
}